// Round 19
// baseline (191.112 us; speedup 1.0000x reference)
//
#include <hip/hip_runtime.h>

#define BB 8
#define NN 2048
#define KK 16
#define QT 64      // queries per scan block
#define HSLICE 8   // slices per half
#define HSLEN 128  // cands per slice (half = 1024 cands)
#define KP 18      // packed keep-depth per slice (validated margin for 128-cand slices)

typedef short bf16x8 __attribute__((ext_vector_type(8)));
typedef float f32x4 __attribute__((ext_vector_type(4)));
typedef unsigned short ushort8v __attribute__((ext_vector_type(8)));

__device__ __forceinline__ float4 f4max(float4 a, float4 b) {
  return make_float4(fmaxf(a.x, b.x), fmaxf(a.y, b.y), fmaxf(a.z, b.z), fmaxf(a.w, b.w));
}

__device__ __forceinline__ unsigned short f2bf(float x) {  // f32 -> bf16 bits, RNE
  union { float f; unsigned u; } v; v.f = x;
  unsigned r = v.u + 0x7fffu + ((v.u >> 16) & 1u);
  return (unsigned short)(r >> 16);
}
__device__ __forceinline__ float bf2f(unsigned short h) {
  union { unsigned u; float f; } v; v.u = ((unsigned)h) << 16;
  return v.f;
}

// -------------------- kNN scan (half-split) + fused wcomp (blocks >= 512)
// 512 scan blocks = 8 b x 32 tiles x 2 HALVES; 512 threads = 8 waves; wave s
// scans slice s of this half (128 cands, WAVE-UNIFORM -> LDS broadcast).
// LDS ~52KB -> 2 scan blocks/CU -> 4 waves/SIMD during scan (vs r15's 2):
// hides the serial chain's dep latency that capped knn at 69us. Per-thread
// structure identical to r15 (VGPR ~52). In-block merge (exact v' recompute,
// stable strict-> insert) emits per-half top-16 (value,id) to global; tiny
// merge kernel combines the two exactly-sorted lists (half0 first + strict >
// reproduces the exact (v, idx) tie-break). Values are passed through memory
// so no cross-kernel FP-reassociation concern.
__global__ __launch_bounds__(512) void knn_scan_kernel(
    const float* __restrict__ pts,
    float* __restrict__ halfv, unsigned short* __restrict__ halfi,
    const float* __restrict__ lin1_w, const float* __restrict__ lin1_b,
    const float* __restrict__ conv1_w, const float* __restrict__ conv1_b,
    const float* __restrict__ lin2_w, const float* __restrict__ lin2_b,
    const float* __restrict__ conv2_w, const float* __restrict__ conv2_b,
    unsigned short* __restrict__ w1hi, unsigned short* __restrict__ w1lo,
    float* __restrict__ b1p,
    unsigned short* __restrict__ w2hi, unsigned short* __restrict__ w2lo,
    float* __restrict__ b2p) {
  __shared__ float4 sp[1024];                       // 16 KB this half's cands
  __shared__ float4 qp[QT];                         // 1 KB queries (2x,2y,2z)
  __shared__ unsigned char  pk[HSLICE][QT][KP];     // 9.2 KB packed-scan ids
  __shared__ float          s1v[4][QT][17];         // 17.4 KB (pad-17: conflict-free)
  __shared__ unsigned short s1i[4][QT][17];         // 8.7 KB
  const int tid = threadIdx.x;

  if (blockIdx.x >= 512) {        // ---- fused wcomp path (no LDS use)
    const int gt = (blockIdx.x - 512) * 512 + tid;
    if (gt < 8192) {              // W1' = conv1_w(128x64) @ lin1_w(64x64)
      const int o = gt >> 6, c = gt & 63;
      float acc = 0.f;
#pragma unroll 8
      for (int k = 0; k < 64; ++k) acc += conv1_w[o * 64 + k] * lin1_w[k * 64 + c];
      const unsigned short h = f2bf(acc);
      w1hi[o * 64 + c] = h;
      w1lo[o * 64 + c] = f2bf(acc - bf2f(h));
      if (c == 0) {
        float bb = conv1_b[o];
        for (int k = 0; k < 64; ++k) bb += conv1_w[o * 64 + k] * lin1_b[k];
        b1p[o] = bb;
      }
    } else if (gt < 8192 + 131072) {  // W2' = conv2_w(1024x128) @ lin2_w(128x128)
      const int t2 = gt - 8192;
      const int o = t2 >> 7, c = t2 & 127;
      float acc = 0.f;
#pragma unroll 8
      for (int k = 0; k < 128; ++k) acc += conv2_w[o * 128 + k] * lin2_w[k * 128 + c];
      const unsigned short h = f2bf(acc);
      w2hi[o * 128 + c] = h;
      w2lo[o * 128 + c] = f2bf(acc - bf2f(h));
      if (c == 0) {
        float bb = conv2_b[o];
        for (int k = 0; k < 128; ++k) bb += conv2_w[o * 128 + k] * lin2_b[k];
        b2p[o] = bb;
      }
    }
    return;
  }

  const int b = blockIdx.x & 7;          // batch -> XCD affinity
  const int t2 = blockIdx.x >> 3;        // 0..63
  const int tile = t2 >> 1;              // 0..31
  const int half = t2 & 1;               // candidate half
  const int q = tid & 63;
  const int s = tid >> 6;                // wave id = slice id (0..7)

  for (int i = tid; i < 1024; i += 512) {
    const size_t gi = (size_t)(b * NN + half * 1024 + i) * 3;
    float x = pts[gi + 0], y = pts[gi + 1], z = pts[gi + 2];
    sp[i] = make_float4(x, y, z, fmaf(x, x, fmaf(y, y, z * z)));
  }
  if (tid < QT) {
    const size_t gq = (size_t)(b * NN + tile * QT + tid) * 3;
    qp[tid] = make_float4(2.f * pts[gq + 0], 2.f * pts[gq + 1], 2.f * pts[gq + 2], 0.f);
  }
  __syncthreads();

  // ---- packed scan of slice s (128 cands, wave-uniform addresses) for query q
  {
    const float4 pq = qp[q];
    unsigned qk[KP];
#pragma unroll
    for (int j = 0; j < KP; ++j) qk[j] = 0u;
    const int m0 = s * HSLEN;
    for (int mb = 0; mb < HSLEN; mb += 8) {
      float4 c[8];
#pragma unroll
      for (int u = 0; u < 8; ++u) c[u] = sp[m0 + mb + u];   // broadcast reads
#pragma unroll
      for (int u = 0; u < 8; ++u) {
        const float v = fmaf(pq.x, c[u].x, fmaf(pq.y, c[u].y, fmaf(pq.z, c[u].z, -c[u].w)));
        unsigned uu = __float_as_uint(v);
        unsigned key = uu ^ ((unsigned)(((int)uu) >> 31) | 0x80000000u);
        unsigned run = (key & 0xFFFFFF00u) | (unsigned)(255 - (mb + u));
#pragma unroll
        for (int j = 0; j < KP; ++j) {          // branchless sorted insert
          const unsigned hi = max(qk[j], run);
          const unsigned lo = min(qk[j], run);
          qk[j] = hi; run = lo;
        }
      }
    }
#pragma unroll
    for (int j = 0; j < KP; ++j) pk[s][q][j] = (unsigned char)(qk[j] & 0xFFu);
  }
  __syncthreads();

  // ---- stage 1: 256 threads (q2, pr in 0..3): merge 2 slices x 18 each
  if (tid < 256) {
    const int q2 = tid & 63, pr = tid >> 6;
    const float4 pq = qp[q2];
    float mv[16]; int mi[16];
#pragma unroll
    for (int j = 0; j < 16; ++j) { mv[j] = -3.0e38f; mi[j] = 0; }
#pragma unroll 1
    for (int ss = 2 * pr; ss <= 2 * pr + 1; ++ss) {
      const int base = ss * HSLEN;
#pragma unroll 1
      for (int j = 0; j < KP; ++j) {
        const int id = base + 255 - (int)pk[ss][q2][j];
        const float4 c = sp[id];
        const float v = fmaf(pq.x, c.x, fmaf(pq.y, c.y, fmaf(pq.z, c.z, -c.w)));
        if (v <= mv[15]) break;                 // list sorted desc: rest can't insert
        mv[15] = v; mi[15] = id;
#pragma unroll
        for (int t = 15; t > 0; --t) {
          if (mv[t] > mv[t - 1]) {
            float tv = mv[t]; mv[t] = mv[t - 1]; mv[t - 1] = tv;
            int ti = mi[t]; mi[t] = mi[t - 1]; mi[t - 1] = ti;
          }
        }
      }
    }
#pragma unroll
    for (int j = 0; j < 16; ++j) {
      s1v[pr][q2][j] = mv[j];
      s1i[pr][q2][j] = (unsigned short)mi[j];
    }
  }
  __syncthreads();

  // ---- stage 2: 64 threads merge 4 exactly-sorted lists -> per-half top-16
  if (tid < QT) {
    float mv[16]; int mi[16];
#pragma unroll
    for (int j = 0; j < 16; ++j) { mv[j] = -3.0e38f; mi[j] = 0; }
#pragma unroll 1
    for (int pr = 0; pr < 4; ++pr) {
#pragma unroll 1
      for (int j = 0; j < 16; ++j) {
        const float v = s1v[pr][tid][j];
        if (v <= mv[15]) break;                 // exact-sorted: rest can't insert
        const int id = s1i[pr][tid][j];
        mv[15] = v; mi[15] = id;
#pragma unroll
        for (int t = 15; t > 0; --t) {
          if (mv[t] > mv[t - 1]) {
            float tv = mv[t]; mv[t] = mv[t - 1]; mv[t - 1] = tv;
            int ti = mi[t]; mi[t] = mi[t - 1]; mi[t - 1] = ti;
          }
        }
      }
    }
    const size_t bn = (size_t)(b * NN + tile * QT + tid);
#pragma unroll
    for (int j = 0; j < 16; ++j) {
      halfv[bn * 32 + half * 16 + j] = mv[j];
      halfi[bn * 32 + half * 16 + j] = (unsigned short)(half * 1024 + mi[j]);
    }
  }
}

// ---- final merge: 2 exactly-sorted 16-lists per query -> exact top-16
__global__ __launch_bounds__(128) void knn_merge_kernel(
    const float* __restrict__ halfv, const unsigned short* __restrict__ halfi,
    int* __restrict__ knn_idx) {
  const size_t bn = (size_t)blockIdx.x * 128 + threadIdx.x;   // 16384 queries
  const float* hv = &halfv[bn * 32];
  const unsigned short* hi = &halfi[bn * 32];
  float mv[16]; int mi[16];
#pragma unroll
  for (int j = 0; j < 16; ++j) { mv[j] = -3.0e38f; mi[j] = 0; }
#pragma unroll 1
  for (int h = 0; h < 2; ++h) {        // half0 first: lower ids win ties
#pragma unroll 1
    for (int j = 0; j < 16; ++j) {
      const float v = hv[h * 16 + j];
      if (v <= mv[15]) break;          // half-lists exactly sorted desc
      const int id = hi[h * 16 + j];
      mv[15] = v; mi[15] = id;
#pragma unroll
      for (int t = 15; t > 0; --t) {
        if (mv[t] > mv[t - 1]) {
          float tv = mv[t]; mv[t] = mv[t - 1]; mv[t - 1] = tv;
          int ti = mi[t]; mi[t] = mi[t - 1]; mi[t - 1] = ti;
        }
      }
    }
  }
#pragma unroll
  for (int j = 0; j < 16; ++j) knn_idx[bn * KK + j] = mi[j];
}

// ------------------------------------------- features (pts + cov) + mlp1 x3
__global__ __launch_bounds__(512, 2) void mlp1_kernel(
    const float* __restrict__ pts, const int* __restrict__ knn_idx,
    const float* __restrict__ w1a, const float* __restrict__ b1a,
    const float* __restrict__ w1b, const float* __restrict__ b1b,
    const float* __restrict__ w1c, const float* __restrict__ b1c,
    float* __restrict__ f1) {
  __shared__ float h1[64][64];
  __shared__ float h2[64][64];
  const int tid = threadIdx.x;
  const int p = tid & 63;
  const int ch = tid >> 6;
  const int b = blockIdx.x & 7;
  const int nc = blockIdx.x >> 3;
  const int bn = b * NN + nc * 64 + p;

  const int n0 = knn_idx[(size_t)bn * KK + 0];
  const int n1 = knn_idx[(size_t)bn * KK + 1];
  const float* pp = &pts[(size_t)bn * 3];
  const float* p0 = &pts[((size_t)(b << 11) + n0) * 3];
  const float* p1 = &pts[((size_t)(b << 11) + n1) * 3];
  float in[12];
  in[0] = pp[0]; in[1] = pp[1]; in[2] = pp[2];
  {
    float a0 = p0[0], a1 = p0[1], a2 = p0[2];
    float c0 = p1[0], c1 = p1[1], c2 = p1[2];
    in[3] = a0 * c0; in[4]  = a0 * c1; in[5]  = a0 * c2;
    in[6] = a1 * c0; in[7]  = a1 * c1; in[8]  = a1 * c2;
    in[9] = a2 * c0; in[10] = a2 * c1; in[11] = a2 * c2;
  }

#pragma unroll
  for (int oi = 0; oi < 8; ++oi) {
    const int o = ch * 8 + oi;
    float a = b1a[o];
#pragma unroll
    for (int c = 0; c < 12; ++c) a += w1a[o * 12 + c] * in[c];
    h1[o][p] = fmaxf(a, 0.f);
  }
  __syncthreads();

  {
    float acc[8];
#pragma unroll
    for (int oi = 0; oi < 8; ++oi) acc[oi] = b1b[ch * 8 + oi];
#pragma unroll 1
    for (int cc = 0; cc < 64; cc += 32) {
      float xr[32];
#pragma unroll
      for (int c = 0; c < 32; ++c) xr[c] = h1[cc + c][p];
#pragma unroll
      for (int oi = 0; oi < 8; ++oi) {
        const int o = ch * 8 + oi;
#pragma unroll
        for (int c = 0; c < 32; ++c) acc[oi] += w1b[o * 64 + cc + c] * xr[c];
      }
    }
    __syncthreads();
#pragma unroll
    for (int oi = 0; oi < 8; ++oi) h2[ch * 8 + oi][p] = fmaxf(acc[oi], 0.f);
  }
  __syncthreads();

  {
    float acc[8];
#pragma unroll
    for (int oi = 0; oi < 8; ++oi) acc[oi] = b1c[ch * 8 + oi];
#pragma unroll 1
    for (int cc = 0; cc < 64; cc += 32) {
      float xr[32];
#pragma unroll
      for (int c = 0; c < 32; ++c) xr[c] = h2[cc + c][p];
#pragma unroll
      for (int oi = 0; oi < 8; ++oi) {
        const int o = ch * 8 + oi;
#pragma unroll
        for (int c = 0; c < 32; ++c) acc[oi] += w1c[o * 64 + cc + c] * xr[c];
      }
    }
#pragma unroll
    for (int oi = 0; oi < 8; ++oi)
      f1[(size_t)bn * 64 + ch * 8 + oi] = fmaxf(acc[oi], 0.f);
  }
}

// ------------- maxpool(f1) + composite lin1+conv1 (W1', MFMA) + relu -> f2
__global__ __launch_bounds__(256, 2) void gconv1_kernel(
    const float* __restrict__ f1, const int* __restrict__ knn_idx,
    const unsigned short* __restrict__ w1hi, const unsigned short* __restrict__ w1lo,
    const float* __restrict__ b1p, float* __restrict__ f2) {
  __shared__ __align__(16) unsigned short xls[2][64][64];   // 16 KB hi|lo
  const int b = blockIdx.x & 7, nc = blockIdx.x >> 3;
  const int tid = threadIdx.x;
  const int lane = tid & 63, wv = tid >> 6;

  {
    const int p = tid & 63, ch = tid >> 6;   // ch in 0..3: channels [ch*16,+16)
    const int bn = b * NN + nc * 64 + p;
    const int4* idr = (const int4*)&knn_idx[(size_t)bn * KK];
    int4 nb4[4];
#pragma unroll
    for (int q = 0; q < 4; ++q) nb4[q] = idr[q];
    float4 mx[4];
#pragma unroll
    for (int q = 0; q < 4; ++q) mx[q] = make_float4(-3e38f, -3e38f, -3e38f, -3e38f);
#pragma unroll
    for (int j = 0; j < KK; ++j) {
      const int nb = (j & 3) == 0 ? nb4[j >> 2].x : (j & 3) == 1 ? nb4[j >> 2].y
                   : (j & 3) == 2 ? nb4[j >> 2].z : nb4[j >> 2].w;
      const float4* v = (const float4*)&f1[((size_t)(b << 11) + nb) * 64 + ch * 16];
#pragma unroll
      for (int q = 0; q < 4; ++q) mx[q] = f4max(mx[q], v[q]);
    }
    char* basep = (char*)&xls[0][0][0];
#pragma unroll
    for (int s = 0; s < 2; ++s) {
      float xv[8] = {mx[2 * s].x, mx[2 * s].y, mx[2 * s].z, mx[2 * s].w,
                     mx[2 * s + 1].x, mx[2 * s + 1].y, mx[2 * s + 1].z, mx[2 * s + 1].w};
      ushort8v hw, lw;
#pragma unroll
      for (int j = 0; j < 8; ++j) {
        unsigned short h = f2bf(xv[j]);
        hw[j] = h;
        lw[j] = f2bf(xv[j] - bf2f(h));
      }
      const int slot = ch * 2 + s;
      const int swz = slot ^ (p & 7);
      char* dst = basep + p * 128 + swz * 16;
      *(ushort8v*)dst = hw;
      *(ushort8v*)(dst + 8192) = lw;
    }
  }
  __syncthreads();

  const int g = lane >> 4, r = lane & 15;
  const char* basep = (const char*)&xls[0][0][0];
  bf16x8 ah[4][2], al[4][2];
#pragma unroll
  for (int m = 0; m < 4; ++m) {
    const int row = m * 16 + r;
#pragma unroll
    for (int kt = 0; kt < 2; ++kt) {
      const int swz = (kt * 4 + g) ^ (row & 7);
      const char* p = basep + row * 128 + swz * 16;
      ah[m][kt] = *(const bf16x8*)p;
      al[m][kt] = *(const bf16x8*)(p + 8192);
    }
  }
  f32x4 acc[4][2];
#pragma unroll
  for (int m = 0; m < 4; ++m)
#pragma unroll
    for (int nt = 0; nt < 2; ++nt) acc[m][nt] = (f32x4){0.f, 0.f, 0.f, 0.f};

#pragma unroll
  for (int nt = 0; nt < 2; ++nt) {
    const int o = (wv * 2 + nt) * 16 + r;
    const char* wb = (const char*)w1hi + (size_t)o * 128 + g * 16;
    const char* lb = (const char*)w1lo + (size_t)o * 128 + g * 16;
    bf16x8 bh[2], bl[2];
#pragma unroll
    for (int kt = 0; kt < 2; ++kt) {
      bh[kt] = *(const bf16x8*)(wb + kt * 64);
      bl[kt] = *(const bf16x8*)(lb + kt * 64);
    }
#pragma unroll
    for (int kt = 0; kt < 2; ++kt) {
#pragma unroll
      for (int m = 0; m < 4; ++m) {
        acc[m][nt] = __builtin_amdgcn_mfma_f32_16x16x32_bf16(ah[m][kt], bh[kt], acc[m][nt], 0, 0, 0);
        acc[m][nt] = __builtin_amdgcn_mfma_f32_16x16x32_bf16(ah[m][kt], bl[kt], acc[m][nt], 0, 0, 0);
        acc[m][nt] = __builtin_amdgcn_mfma_f32_16x16x32_bf16(al[m][kt], bh[kt], acc[m][nt], 0, 0, 0);
      }
    }
  }
#pragma unroll
  for (int nt = 0; nt < 2; ++nt) {
    const int o = (wv * 2 + nt) * 16 + r;
    const float bias = b1p[o];
#pragma unroll
    for (int m = 0; m < 4; ++m) {
#pragma unroll
      for (int j = 0; j < 4; ++j) {
        const int row = m * 16 + g * 4 + j;
        f2[((size_t)(b * NN + nc * 64 + row)) * 128 + o] = fmaxf(acc[m][nt][j] + bias, 0.f);
      }
    }
  }
}

// ---- maxpool(f2) + composite lin2+conv2 (W2', MFMA) + fused global max(n)
__global__ __launch_bounds__(256, 2) void gconv2max_kernel(
    const float* __restrict__ f2, const int* __restrict__ knn_idx,
    const unsigned short* __restrict__ w2hi, const unsigned short* __restrict__ w2lo,
    float* __restrict__ pmax) {
  __shared__ __align__(16) unsigned short xls[2][64][128];   // 32 KB hi|lo
  const int b = blockIdx.x & 7, nc = blockIdx.x >> 3;
  const int tid = threadIdx.x;
  const int lane = tid & 63, wv = tid >> 6;

  {
    const int p = tid & 63, ch = tid >> 6;   // ch in 0..3: channels [ch*32,+32)
    const int bn = b * NN + nc * 64 + p;
    const int4* idr = (const int4*)&knn_idx[(size_t)bn * KK];
    int4 nb4[4];
#pragma unroll
    for (int q = 0; q < 4; ++q) nb4[q] = idr[q];
    float4 mx[8];
#pragma unroll
    for (int q = 0; q < 8; ++q) mx[q] = make_float4(-3e38f, -3e38f, -3e38f, -3e38f);
#pragma unroll
    for (int j = 0; j < KK; ++j) {
      const int nb = (j & 3) == 0 ? nb4[j >> 2].x : (j & 3) == 1 ? nb4[j >> 2].y
                   : (j & 3) == 2 ? nb4[j >> 2].z : nb4[j >> 2].w;
      const float4* v = (const float4*)&f2[((size_t)(b << 11) + nb) * 128 + ch * 32];
#pragma unroll
      for (int q = 0; q < 8; ++q) mx[q] = f4max(mx[q], v[q]);
    }
    char* basep = (char*)&xls[0][0][0];
#pragma unroll
    for (int s = 0; s < 4; ++s) {
      float xv[8] = {mx[2 * s].x, mx[2 * s].y, mx[2 * s].z, mx[2 * s].w,
                     mx[2 * s + 1].x, mx[2 * s + 1].y, mx[2 * s + 1].z, mx[2 * s + 1].w};
      ushort8v hw, lw;
#pragma unroll
      for (int j = 0; j < 8; ++j) {
        unsigned short h = f2bf(xv[j]);
        hw[j] = h;
        lw[j] = f2bf(xv[j] - bf2f(h));
      }
      const int slot = ch * 4 + s;
      const int swz = slot ^ (p & 15);
      char* dst = basep + p * 256 + swz * 16;
      *(ushort8v*)dst = hw;
      *(ushort8v*)(dst + 16384) = lw;
    }
  }
  __syncthreads();

  const int g = lane >> 4, r = lane & 15;
  const char* basep = (const char*)&xls[0][0][0];
  float omax[16];
#pragma unroll
  for (int ot = 0; ot < 16; ++ot) omax[ot] = -3e38f;

#pragma unroll
  for (int mg = 0; mg < 2; ++mg) {
    bf16x8 ah[2][4], al[2][4];
#pragma unroll
    for (int m = 0; m < 2; ++m) {
      const int row = (mg * 2 + m) * 16 + r;
#pragma unroll
      for (int kt = 0; kt < 4; ++kt) {
        const int swz = (kt * 4 + g) ^ (row & 15);
        const char* p = basep + row * 256 + swz * 16;
        ah[m][kt] = *(const bf16x8*)p;
        al[m][kt] = *(const bf16x8*)(p + 16384);
      }
    }
#pragma unroll 1
    for (int ot = 0; ot < 16; ++ot) {
      const int o = wv * 256 + ot * 16 + r;
      const char* wb = (const char*)w2hi + (size_t)o * 256 + g * 16;
      const char* lb = (const char*)w2lo + (size_t)o * 256 + g * 16;
      bf16x8 bh[4], bl[4];
#pragma unroll
      for (int kt = 0; kt < 4; ++kt) {
        bh[kt] = *(const bf16x8*)(wb + kt * 64);
        bl[kt] = *(const bf16x8*)(lb + kt * 64);
      }
      f32x4 acc0 = {0.f, 0.f, 0.f, 0.f}, acc1 = {0.f, 0.f, 0.f, 0.f};
#pragma unroll
      for (int kt = 0; kt < 4; ++kt) {
        acc0 = __builtin_amdgcn_mfma_f32_16x16x32_bf16(ah[0][kt], bh[kt], acc0, 0, 0, 0);
        acc1 = __builtin_amdgcn_mfma_f32_16x16x32_bf16(ah[1][kt], bh[kt], acc1, 0, 0, 0);
        acc0 = __builtin_amdgcn_mfma_f32_16x16x32_bf16(ah[0][kt], bl[kt], acc0, 0, 0, 0);
        acc1 = __builtin_amdgcn_mfma_f32_16x16x32_bf16(ah[1][kt], bl[kt], acc1, 0, 0, 0);
        acc0 = __builtin_amdgcn_mfma_f32_16x16x32_bf16(al[0][kt], bh[kt], acc0, 0, 0, 0);
        acc1 = __builtin_amdgcn_mfma_f32_16x16x32_bf16(al[1][kt], bh[kt], acc1, 0, 0, 0);
      }
      float mx = fmaxf(fmaxf(fmaxf(acc0[0], acc0[1]), fmaxf(acc0[2], acc0[3])),
                       fmaxf(fmaxf(acc1[0], acc1[1]), fmaxf(acc1[2], acc1[3])));
      omax[ot] = fmaxf(omax[ot], mx);
    }
  }
#pragma unroll
  for (int ot = 0; ot < 16; ++ot) {
    float v = omax[ot];
    v = fmaxf(v, __shfl_xor(v, 16, 64));
    v = fmaxf(v, __shfl_xor(v, 32, 64));
    omax[ot] = v;
  }
  if (lane < 16) {
#pragma unroll
    for (int ot = 0; ot < 16; ++ot) {
      const int o = wv * 256 + ot * 16 + lane;
      pmax[((size_t)b * 1024 + o) * 32 + nc] = omax[ot];
    }
  }
}

// ------------------- head stage 0: reduce pmax chunks + b2' -> g[8][1024]
__global__ __launch_bounds__(256) void head_g_kernel(
    const float* __restrict__ pmax, const float* __restrict__ b2p,
    float* __restrict__ gbuf) {
  const int b = blockIdx.x & 7;
  const int o = (blockIdx.x >> 3) * 256 + threadIdx.x;
  const float4* p = (const float4*)&pmax[((size_t)b * 1024 + o) * 32];
  float4 a4 = p[0];
#pragma unroll
  for (int gi = 1; gi < 8; ++gi) a4 = f4max(a4, p[gi]);
  gbuf[b * 1024 + o] = fmaxf(fmaxf(a4.x, a4.y), fmaxf(a4.z, a4.w)) + b2p[o];
}

// ------------------- head stage 1: h = relu(w2a @ g + b2a), wave-per-output
__global__ __launch_bounds__(256) void head_a_kernel(
    const float* __restrict__ gbuf, const float* __restrict__ w2a,
    const float* __restrict__ b2a, float* __restrict__ hbuf) {
  const int b = blockIdx.x & 7;
  const int k = (blockIdx.x >> 3) * 4 + (threadIdx.x >> 6);   // wave-per-output
  const int lane = threadIdx.x & 63;
  const float4* wr = (const float4*)&w2a[(size_t)k * 1024];
  const float4* gv = (const float4*)&gbuf[b * 1024];
  float a = 0.f;
#pragma unroll
  for (int i = 0; i < 4; ++i) {               // coalesced: f4 idx lane + i*64
    float4 w = wr[lane + i * 64], xx = gv[lane + i * 64];
    a += w.x * xx.x + w.y * xx.y + w.z * xx.z + w.w * xx.w;
  }
#pragma unroll
  for (int s = 32; s >= 1; s >>= 1) a += __shfl_xor(a, s, 64);
  if (lane == 0) hbuf[b * 512 + k] = fmaxf(a + b2a[k], 0.f);
}

// ------------------- head stage 2: out = w2b @ h + b2b, wave-per-output
__global__ __launch_bounds__(256) void head_b_kernel(
    const float* __restrict__ hbuf, const float* __restrict__ w2b,
    const float* __restrict__ b2b, float* __restrict__ out) {
  const int b = blockIdx.x & 7;
  const int k = (blockIdx.x >> 3) * 4 + (threadIdx.x >> 6);
  const int lane = threadIdx.x & 63;
  const float4* wr = (const float4*)&w2b[(size_t)k * 512];
  const float4* hv = (const float4*)&hbuf[b * 512];
  float a = 0.f;
#pragma unroll
  for (int i = 0; i < 2; ++i) {
    float4 w = wr[lane + i * 64], xx = hv[lane + i * 64];
    a += w.x * xx.x + w.y * xx.y + w.z * xx.z + w.w * xx.w;
  }
#pragma unroll
  for (int s = 32; s >= 1; s >>= 1) a += __shfl_xor(a, s, 64);
  if (lane == 0) out[b * 512 + k] = a + b2b[k];
}

extern "C" void kernel_launch(void* const* d_in, const int* in_sizes, int n_in,
                              void* d_out, int out_size, void* d_ws, size_t ws_size,
                              hipStream_t stream) {
  const float* pts     = (const float*)d_in[0];
  const float* w1a     = (const float*)d_in[1];
  const float* b1a     = (const float*)d_in[2];
  const float* w1b     = (const float*)d_in[3];
  const float* b1b     = (const float*)d_in[4];
  const float* w1c     = (const float*)d_in[5];
  const float* b1c     = (const float*)d_in[6];
  const float* lin1_w  = (const float*)d_in[7];
  const float* lin1_b  = (const float*)d_in[8];
  const float* conv1_w = (const float*)d_in[9];
  const float* conv1_b = (const float*)d_in[10];
  const float* lin2_w  = (const float*)d_in[11];
  const float* lin2_b  = (const float*)d_in[12];
  const float* conv2_w = (const float*)d_in[13];
  const float* conv2_b = (const float*)d_in[14];
  const float* w2a     = (const float*)d_in[15];
  const float* b2a     = (const float*)d_in[16];
  const float* w2b     = (const float*)d_in[17];
  const float* b2b     = (const float*)d_in[18];

  char* ws = (char*)d_ws;
  int*   knn_idx = (int*)ws;                              // 0 .. 1M
  float* f1  = (float*)(ws + (1u << 20));                 // 1M .. 5M
  float* pm  = (float*)(ws + (5u << 20));                 // 5M .. 6M
  unsigned short* w2hi = (unsigned short*)(ws + (6u << 20));               // 256K
  unsigned short* w2lo = (unsigned short*)(ws + (6u << 20) + (1u << 18));  // 256K
  unsigned short* w1hi = (unsigned short*)(ws + (6u << 20) + (2u << 18));  // 16K
  unsigned short* w1lo = (unsigned short*)(ws + (6u << 20) + (2u << 18) + (1u << 14));
  float* b1p = (float*)(ws + (6u << 20) + (2u << 18) + (2u << 14));        // 512B
  float* b2p = (float*)(ws + (6u << 20) + (2u << 18) + (3u << 14));        // 4K
  float* gbuf = (float*)(ws + (7u << 20));                // 32K
  float* hbuf = (float*)(ws + (7u << 20) + (1u << 16));   // 16K
  float* f2  = (float*)(ws + (9u << 20));                 // 9M .. 17M
  float* halfv = (float*)(ws + (17u << 20));              // 17M .. 19M (2MB)
  unsigned short* halfi = (unsigned short*)(ws + (19u << 20)); // 19M .. 20M (1MB)

  knn_scan_kernel<<<784, 512, 0, stream>>>(pts, halfv, halfi,
                                           lin1_w, lin1_b, conv1_w, conv1_b,
                                           lin2_w, lin2_b, conv2_w, conv2_b,
                                           w1hi, w1lo, b1p, w2hi, w2lo, b2p);
  knn_merge_kernel<<<128, 128, 0, stream>>>(halfv, halfi, knn_idx);
  mlp1_kernel  <<<256, 512, 0, stream>>>(pts, knn_idx, w1a, b1a, w1b, b1b, w1c, b1c, f1);
  gconv1_kernel<<<256, 256, 0, stream>>>(f1, knn_idx, w1hi, w1lo, b1p, f2);
  gconv2max_kernel<<<256, 256, 0, stream>>>(f2, knn_idx, w2hi, w2lo, pm);
  head_g_kernel<<<32, 256, 0, stream>>>(pm, b2p, gbuf);
  head_a_kernel<<<1024, 256, 0, stream>>>(gbuf, w2a, b2a, hbuf);
  head_b_kernel<<<1024, 256, 0, stream>>>(hbuf, w2b, b2b, (float*)d_out);
}

// Round 20
// 169.541 us; speedup vs baseline: 1.1272x; 1.1272x over previous
//
#include <hip/hip_runtime.h>

#define BB 8
#define NN 2048
#define KK 16
#define QT 64      // kNN queries per block (wave-uniform candidate streams)
#define NSLICE 8
#define SLEN 256   // NN / NSLICE
#define KP 18      // packed keep-depth per slice (pool safety margin)

typedef short bf16x8 __attribute__((ext_vector_type(8)));
typedef float f32x4 __attribute__((ext_vector_type(4)));
typedef unsigned short ushort8v __attribute__((ext_vector_type(8)));

__device__ __forceinline__ float4 f4max(float4 a, float4 b) {
  return make_float4(fmaxf(a.x, b.x), fmaxf(a.y, b.y), fmaxf(a.z, b.z), fmaxf(a.w, b.w));
}

__device__ __forceinline__ unsigned short f2bf(float x) {  // f32 -> bf16 bits, RNE
  union { float f; unsigned u; } v; v.f = x;
  unsigned r = v.u + 0x7fffu + ((v.u >> 16) & 1u);
  return (unsigned short)(r >> 16);
}
__device__ __forceinline__ float bf2f(unsigned short h) {
  union { unsigned u; float f; } v; v.u = ((unsigned)h) << 16;
  return v.f;
}

// --------------------------- kNN top-16  (+ fused wcomp in blocks >= 256)
// REVERTED to round-18 best-measured state (total 169.6us, knn 69.5us).
// knn path: blocks 0..255 = 8 b x 32 tiles of 64 queries; 512 threads = 8
// waves; wave s scans slice s (256 cands) -> scan addresses WAVE-UNIFORM ->
// LDS broadcast. Blocks 256..543 run the independent composite-weight setup
// co-resident with knn blocks (136KB LDS <= 160KB/CU, 16 waves) so wcomp
// executes inside knn's shadow. r19's half-split regressed (VGPR 40 remat +
// doubled merge work); design space bracketed over 10 experiments.
__global__ __launch_bounds__(512) void knn_kernel(
    const float* __restrict__ pts, int* __restrict__ knn_idx,
    const float* __restrict__ lin1_w, const float* __restrict__ lin1_b,
    const float* __restrict__ conv1_w, const float* __restrict__ conv1_b,
    const float* __restrict__ lin2_w, const float* __restrict__ lin2_b,
    const float* __restrict__ conv2_w, const float* __restrict__ conv2_b,
    unsigned short* __restrict__ w1hi, unsigned short* __restrict__ w1lo,
    float* __restrict__ b1p,
    unsigned short* __restrict__ w2hi, unsigned short* __restrict__ w2lo,
    float* __restrict__ b2p) {
  __shared__ float4 sp[NN];                         // 32 KB (x,y,z,|p|^2)
  __shared__ unsigned char  pk[NSLICE][QT][KP];     // 9 KB packed-scan ids
  __shared__ float          s1v[4][QT][17];         // 17 KB (pad: conflict-free)
  __shared__ unsigned short s1i[4][QT][17];         // 8.5 KB
  const int tid = threadIdx.x;

  if (blockIdx.x >= 256) {        // ---- fused wcomp path (no LDS, no sync)
    const int gt = (blockIdx.x - 256) * 512 + tid;
    if (gt < 8192) {              // W1' = conv1_w(128x64) @ lin1_w(64x64)
      const int o = gt >> 6, c = gt & 63;
      float acc = 0.f;
#pragma unroll 8
      for (int k = 0; k < 64; ++k) acc += conv1_w[o * 64 + k] * lin1_w[k * 64 + c];
      const unsigned short h = f2bf(acc);
      w1hi[o * 64 + c] = h;
      w1lo[o * 64 + c] = f2bf(acc - bf2f(h));
      if (c == 0) {
        float bb = conv1_b[o];
        for (int k = 0; k < 64; ++k) bb += conv1_w[o * 64 + k] * lin1_b[k];
        b1p[o] = bb;
      }
    } else if (gt < 8192 + 131072) {  // W2' = conv2_w(1024x128) @ lin2_w(128x128)
      const int t2 = gt - 8192;
      const int o = t2 >> 7, c = t2 & 127;
      float acc = 0.f;
#pragma unroll 8
      for (int k = 0; k < 128; ++k) acc += conv2_w[o * 128 + k] * lin2_w[k * 128 + c];
      const unsigned short h = f2bf(acc);
      w2hi[o * 128 + c] = h;
      w2lo[o * 128 + c] = f2bf(acc - bf2f(h));
      if (c == 0) {
        float bb = conv2_b[o];
        for (int k = 0; k < 128; ++k) bb += conv2_w[o * 128 + k] * lin2_b[k];
        b2p[o] = bb;
      }
    }
    return;
  }

  const int b = blockIdx.x & 7;
  const int tile = blockIdx.x >> 3;
  const int q = tid & 63;
  const int s = tid >> 6;          // wave id = slice id

  for (int i = tid; i < NN; i += 512) {
    float x = pts[(size_t)(b * NN + i) * 3 + 0];
    float y = pts[(size_t)(b * NN + i) * 3 + 1];
    float z = pts[(size_t)(b * NN + i) * 3 + 2];
    sp[i] = make_float4(x, y, z, x * x + y * y + z * z);
  }
  __syncthreads();

  // ---- packed scan of slice s (256 cands, wave-uniform addresses) for query q
  {
    const float4 pq = sp[tile * QT + q];
    const float qx = 2.f * pq.x, qy = 2.f * pq.y, qz = 2.f * pq.z;
    unsigned qk[KP];
#pragma unroll
    for (int j = 0; j < KP; ++j) qk[j] = 0u;
    const int m0 = s * SLEN;
    for (int mb = 0; mb < SLEN; mb += 8) {
      float4 c[8];
#pragma unroll
      for (int u = 0; u < 8; ++u) c[u] = sp[m0 + mb + u];   // broadcast reads
#pragma unroll
      for (int u = 0; u < 8; ++u) {
        const float v = fmaf(qx, c[u].x, fmaf(qy, c[u].y, fmaf(qz, c[u].z, -c[u].w)));
        unsigned uu = __float_as_uint(v);
        unsigned key = uu ^ ((unsigned)(((int)uu) >> 31) | 0x80000000u);
        unsigned run = (key & 0xFFFFFF00u) | (unsigned)(255 - (mb + u));
#pragma unroll
        for (int j = 0; j < KP; ++j) {          // branchless sorted insert
          const unsigned hi = max(qk[j], run);
          const unsigned lo = min(qk[j], run);
          qk[j] = hi; run = lo;
        }
      }
    }
#pragma unroll
    for (int j = 0; j < KP; ++j) pk[s][q][j] = (unsigned char)(qk[j] & 0xFFu);
  }
  __syncthreads();

  // ---- stage 1: 256 threads (q2 = tid&63, pr = tid>>6): merge 2 slices x 18
  //      (exact v' recompute; packed list sorted desc -> early-break safe)
  if (tid < 256) {
    const int q2 = tid & 63, pr = tid >> 6;
    const float4 pm = sp[tile * QT + q2];
    const float qx = 2.f * pm.x, qy = 2.f * pm.y, qz = 2.f * pm.z;
    float mv[16]; int mi[16];
#pragma unroll
    for (int j = 0; j < 16; ++j) { mv[j] = -3.0e38f; mi[j] = 0; }
#pragma unroll 1
    for (int ss = 2 * pr; ss <= 2 * pr + 1; ++ss) {
      const int base = ss * SLEN;
#pragma unroll 1
      for (int j = 0; j < KP; ++j) {
        const int id = base + 255 - (int)pk[ss][q2][j];
        const float4 c = sp[id];
        const float v = fmaf(qx, c.x, fmaf(qy, c.y, fmaf(qz, c.z, -c.w)));
        if (v <= mv[15]) break;                 // list sorted desc: rest can't insert
        mv[15] = v; mi[15] = id;
#pragma unroll
        for (int t = 15; t > 0; --t) {
          if (mv[t] > mv[t - 1]) {
            float tv = mv[t]; mv[t] = mv[t - 1]; mv[t - 1] = tv;
            int ti = mi[t]; mi[t] = mi[t - 1]; mi[t - 1] = ti;
          }
        }
      }
    }
#pragma unroll
    for (int j = 0; j < 16; ++j) {
      s1v[pr][q2][j] = mv[j];
      s1i[pr][q2][j] = (unsigned short)mi[j];
    }
  }
  __syncthreads();

  // ---- stage 2: 64 threads merge 4 exactly-sorted lists (early-break safe)
  if (tid < QT) {
    float mv[16]; int mi[16];
#pragma unroll
    for (int j = 0; j < 16; ++j) { mv[j] = -3.0e38f; mi[j] = 0; }
#pragma unroll 1
    for (int pr = 0; pr < 4; ++pr) {
#pragma unroll 1
      for (int j = 0; j < 16; ++j) {
        const float v = s1v[pr][tid][j];
        if (v <= mv[15]) break;                 // exact-sorted: rest can't insert
        const int id = s1i[pr][tid][j];
        mv[15] = v; mi[15] = id;
#pragma unroll
        for (int t = 15; t > 0; --t) {
          if (mv[t] > mv[t - 1]) {
            float tv = mv[t]; mv[t] = mv[t - 1]; mv[t - 1] = tv;
            int ti = mi[t]; mi[t] = mi[t - 1]; mi[t - 1] = ti;
          }
        }
      }
    }
    const int nq = tile * QT + tid;
#pragma unroll
    for (int j = 0; j < 16; ++j) knn_idx[(size_t)(b * NN + nq) * KK + j] = mi[j];
  }
}

// ------------------------------------------- features (pts + cov) + mlp1 x3
__global__ __launch_bounds__(512, 2) void mlp1_kernel(
    const float* __restrict__ pts, const int* __restrict__ knn_idx,
    const float* __restrict__ w1a, const float* __restrict__ b1a,
    const float* __restrict__ w1b, const float* __restrict__ b1b,
    const float* __restrict__ w1c, const float* __restrict__ b1c,
    float* __restrict__ f1) {
  __shared__ float h1[64][64];
  __shared__ float h2[64][64];
  const int tid = threadIdx.x;
  const int p = tid & 63;
  const int ch = tid >> 6;
  const int b = blockIdx.x & 7;
  const int nc = blockIdx.x >> 3;
  const int bn = b * NN + nc * 64 + p;

  const int n0 = knn_idx[(size_t)bn * KK + 0];
  const int n1 = knn_idx[(size_t)bn * KK + 1];
  const float* pp = &pts[(size_t)bn * 3];
  const float* p0 = &pts[((size_t)(b << 11) + n0) * 3];
  const float* p1 = &pts[((size_t)(b << 11) + n1) * 3];
  float in[12];
  in[0] = pp[0]; in[1] = pp[1]; in[2] = pp[2];
  {
    float a0 = p0[0], a1 = p0[1], a2 = p0[2];
    float c0 = p1[0], c1 = p1[1], c2 = p1[2];
    in[3] = a0 * c0; in[4]  = a0 * c1; in[5]  = a0 * c2;
    in[6] = a1 * c0; in[7]  = a1 * c1; in[8]  = a1 * c2;
    in[9] = a2 * c0; in[10] = a2 * c1; in[11] = a2 * c2;
  }

#pragma unroll
  for (int oi = 0; oi < 8; ++oi) {
    const int o = ch * 8 + oi;
    float a = b1a[o];
#pragma unroll
    for (int c = 0; c < 12; ++c) a += w1a[o * 12 + c] * in[c];
    h1[o][p] = fmaxf(a, 0.f);
  }
  __syncthreads();

  {
    float acc[8];
#pragma unroll
    for (int oi = 0; oi < 8; ++oi) acc[oi] = b1b[ch * 8 + oi];
#pragma unroll 1
    for (int cc = 0; cc < 64; cc += 32) {
      float xr[32];
#pragma unroll
      for (int c = 0; c < 32; ++c) xr[c] = h1[cc + c][p];
#pragma unroll
      for (int oi = 0; oi < 8; ++oi) {
        const int o = ch * 8 + oi;
#pragma unroll
        for (int c = 0; c < 32; ++c) acc[oi] += w1b[o * 64 + cc + c] * xr[c];
      }
    }
    __syncthreads();
#pragma unroll
    for (int oi = 0; oi < 8; ++oi) h2[ch * 8 + oi][p] = fmaxf(acc[oi], 0.f);
  }
  __syncthreads();

  {
    float acc[8];
#pragma unroll
    for (int oi = 0; oi < 8; ++oi) acc[oi] = b1c[ch * 8 + oi];
#pragma unroll 1
    for (int cc = 0; cc < 64; cc += 32) {
      float xr[32];
#pragma unroll
      for (int c = 0; c < 32; ++c) xr[c] = h2[cc + c][p];
#pragma unroll
      for (int oi = 0; oi < 8; ++oi) {
        const int o = ch * 8 + oi;
#pragma unroll
        for (int c = 0; c < 32; ++c) acc[oi] += w1c[o * 64 + cc + c] * xr[c];
      }
    }
#pragma unroll
    for (int oi = 0; oi < 8; ++oi)
      f1[(size_t)bn * 64 + ch * 8 + oi] = fmaxf(acc[oi], 0.f);
  }
}

// ------------- maxpool(f1) + composite lin1+conv1 (W1', MFMA) + relu -> f2
__global__ __launch_bounds__(256, 2) void gconv1_kernel(
    const float* __restrict__ f1, const int* __restrict__ knn_idx,
    const unsigned short* __restrict__ w1hi, const unsigned short* __restrict__ w1lo,
    const float* __restrict__ b1p, float* __restrict__ f2) {
  __shared__ __align__(16) unsigned short xls[2][64][64];   // 16 KB hi|lo
  const int b = blockIdx.x & 7, nc = blockIdx.x >> 3;
  const int tid = threadIdx.x;
  const int lane = tid & 63, wv = tid >> 6;

  {
    const int p = tid & 63, ch = tid >> 6;   // ch in 0..3: channels [ch*16,+16)
    const int bn = b * NN + nc * 64 + p;
    const int4* idr = (const int4*)&knn_idx[(size_t)bn * KK];
    int4 nb4[4];
#pragma unroll
    for (int q = 0; q < 4; ++q) nb4[q] = idr[q];
    float4 mx[4];
#pragma unroll
    for (int q = 0; q < 4; ++q) mx[q] = make_float4(-3e38f, -3e38f, -3e38f, -3e38f);
#pragma unroll
    for (int j = 0; j < KK; ++j) {
      const int nb = (j & 3) == 0 ? nb4[j >> 2].x : (j & 3) == 1 ? nb4[j >> 2].y
                   : (j & 3) == 2 ? nb4[j >> 2].z : nb4[j >> 2].w;
      const float4* v = (const float4*)&f1[((size_t)(b << 11) + nb) * 64 + ch * 16];
#pragma unroll
      for (int q = 0; q < 4; ++q) mx[q] = f4max(mx[q], v[q]);
    }
    char* basep = (char*)&xls[0][0][0];
#pragma unroll
    for (int s = 0; s < 2; ++s) {
      float xv[8] = {mx[2 * s].x, mx[2 * s].y, mx[2 * s].z, mx[2 * s].w,
                     mx[2 * s + 1].x, mx[2 * s + 1].y, mx[2 * s + 1].z, mx[2 * s + 1].w};
      ushort8v hw, lw;
#pragma unroll
      for (int j = 0; j < 8; ++j) {
        unsigned short h = f2bf(xv[j]);
        hw[j] = h;
        lw[j] = f2bf(xv[j] - bf2f(h));
      }
      const int slot = ch * 2 + s;
      const int swz = slot ^ (p & 7);
      char* dst = basep + p * 128 + swz * 16;
      *(ushort8v*)dst = hw;
      *(ushort8v*)(dst + 8192) = lw;
    }
  }
  __syncthreads();

  const int g = lane >> 4, r = lane & 15;
  const char* basep = (const char*)&xls[0][0][0];
  bf16x8 ah[4][2], al[4][2];
#pragma unroll
  for (int m = 0; m < 4; ++m) {
    const int row = m * 16 + r;
#pragma unroll
    for (int kt = 0; kt < 2; ++kt) {
      const int swz = (kt * 4 + g) ^ (row & 7);
      const char* p = basep + row * 128 + swz * 16;
      ah[m][kt] = *(const bf16x8*)p;
      al[m][kt] = *(const bf16x8*)(p + 8192);
    }
  }
  f32x4 acc[4][2];
#pragma unroll
  for (int m = 0; m < 4; ++m)
#pragma unroll
    for (int nt = 0; nt < 2; ++nt) acc[m][nt] = (f32x4){0.f, 0.f, 0.f, 0.f};

#pragma unroll
  for (int nt = 0; nt < 2; ++nt) {
    const int o = (wv * 2 + nt) * 16 + r;
    const char* wb = (const char*)w1hi + (size_t)o * 128 + g * 16;
    const char* lb = (const char*)w1lo + (size_t)o * 128 + g * 16;
    bf16x8 bh[2], bl[2];
#pragma unroll
    for (int kt = 0; kt < 2; ++kt) {
      bh[kt] = *(const bf16x8*)(wb + kt * 64);
      bl[kt] = *(const bf16x8*)(lb + kt * 64);
    }
#pragma unroll
    for (int kt = 0; kt < 2; ++kt) {
#pragma unroll
      for (int m = 0; m < 4; ++m) {
        acc[m][nt] = __builtin_amdgcn_mfma_f32_16x16x32_bf16(ah[m][kt], bh[kt], acc[m][nt], 0, 0, 0);
        acc[m][nt] = __builtin_amdgcn_mfma_f32_16x16x32_bf16(ah[m][kt], bl[kt], acc[m][nt], 0, 0, 0);
        acc[m][nt] = __builtin_amdgcn_mfma_f32_16x16x32_bf16(al[m][kt], bh[kt], acc[m][nt], 0, 0, 0);
      }
    }
  }
#pragma unroll
  for (int nt = 0; nt < 2; ++nt) {
    const int o = (wv * 2 + nt) * 16 + r;
    const float bias = b1p[o];
#pragma unroll
    for (int m = 0; m < 4; ++m) {
#pragma unroll
      for (int j = 0; j < 4; ++j) {
        const int row = m * 16 + g * 4 + j;
        f2[((size_t)(b * NN + nc * 64 + row)) * 128 + o] = fmaxf(acc[m][nt][j] + bias, 0.f);
      }
    }
  }
}

// ---- maxpool(f2) + composite lin2+conv2 (W2', MFMA) + fused global max(n)
__global__ __launch_bounds__(256, 2) void gconv2max_kernel(
    const float* __restrict__ f2, const int* __restrict__ knn_idx,
    const unsigned short* __restrict__ w2hi, const unsigned short* __restrict__ w2lo,
    float* __restrict__ pmax) {
  __shared__ __align__(16) unsigned short xls[2][64][128];   // 32 KB hi|lo
  const int b = blockIdx.x & 7, nc = blockIdx.x >> 3;
  const int tid = threadIdx.x;
  const int lane = tid & 63, wv = tid >> 6;

  {
    const int p = tid & 63, ch = tid >> 6;   // ch in 0..3: channels [ch*32,+32)
    const int bn = b * NN + nc * 64 + p;
    const int4* idr = (const int4*)&knn_idx[(size_t)bn * KK];
    int4 nb4[4];
#pragma unroll
    for (int q = 0; q < 4; ++q) nb4[q] = idr[q];
    float4 mx[8];
#pragma unroll
    for (int q = 0; q < 8; ++q) mx[q] = make_float4(-3e38f, -3e38f, -3e38f, -3e38f);
#pragma unroll
    for (int j = 0; j < KK; ++j) {
      const int nb = (j & 3) == 0 ? nb4[j >> 2].x : (j & 3) == 1 ? nb4[j >> 2].y
                   : (j & 3) == 2 ? nb4[j >> 2].z : nb4[j >> 2].w;
      const float4* v = (const float4*)&f2[((size_t)(b << 11) + nb) * 128 + ch * 32];
#pragma unroll
      for (int q = 0; q < 8; ++q) mx[q] = f4max(mx[q], v[q]);
    }
    char* basep = (char*)&xls[0][0][0];
#pragma unroll
    for (int s = 0; s < 4; ++s) {
      float xv[8] = {mx[2 * s].x, mx[2 * s].y, mx[2 * s].z, mx[2 * s].w,
                     mx[2 * s + 1].x, mx[2 * s + 1].y, mx[2 * s + 1].z, mx[2 * s + 1].w};
      ushort8v hw, lw;
#pragma unroll
      for (int j = 0; j < 8; ++j) {
        unsigned short h = f2bf(xv[j]);
        hw[j] = h;
        lw[j] = f2bf(xv[j] - bf2f(h));
      }
      const int slot = ch * 4 + s;
      const int swz = slot ^ (p & 15);
      char* dst = basep + p * 256 + swz * 16;
      *(ushort8v*)dst = hw;
      *(ushort8v*)(dst + 16384) = lw;
    }
  }
  __syncthreads();

  const int g = lane >> 4, r = lane & 15;
  const char* basep = (const char*)&xls[0][0][0];
  float omax[16];
#pragma unroll
  for (int ot = 0; ot < 16; ++ot) omax[ot] = -3e38f;

#pragma unroll
  for (int mg = 0; mg < 2; ++mg) {
    bf16x8 ah[2][4], al[2][4];
#pragma unroll
    for (int m = 0; m < 2; ++m) {
      const int row = (mg * 2 + m) * 16 + r;
#pragma unroll
      for (int kt = 0; kt < 4; ++kt) {
        const int swz = (kt * 4 + g) ^ (row & 15);
        const char* p = basep + row * 256 + swz * 16;
        ah[m][kt] = *(const bf16x8*)p;
        al[m][kt] = *(const bf16x8*)(p + 16384);
      }
    }
#pragma unroll 1
    for (int ot = 0; ot < 16; ++ot) {
      const int o = wv * 256 + ot * 16 + r;
      const char* wb = (const char*)w2hi + (size_t)o * 256 + g * 16;
      const char* lb = (const char*)w2lo + (size_t)o * 256 + g * 16;
      bf16x8 bh[4], bl[4];
#pragma unroll
      for (int kt = 0; kt < 4; ++kt) {
        bh[kt] = *(const bf16x8*)(wb + kt * 64);
        bl[kt] = *(const bf16x8*)(lb + kt * 64);
      }
      f32x4 acc0 = {0.f, 0.f, 0.f, 0.f}, acc1 = {0.f, 0.f, 0.f, 0.f};
#pragma unroll
      for (int kt = 0; kt < 4; ++kt) {
        acc0 = __builtin_amdgcn_mfma_f32_16x16x32_bf16(ah[0][kt], bh[kt], acc0, 0, 0, 0);
        acc1 = __builtin_amdgcn_mfma_f32_16x16x32_bf16(ah[1][kt], bh[kt], acc1, 0, 0, 0);
        acc0 = __builtin_amdgcn_mfma_f32_16x16x32_bf16(ah[0][kt], bl[kt], acc0, 0, 0, 0);
        acc1 = __builtin_amdgcn_mfma_f32_16x16x32_bf16(ah[1][kt], bl[kt], acc1, 0, 0, 0);
        acc0 = __builtin_amdgcn_mfma_f32_16x16x32_bf16(al[0][kt], bh[kt], acc0, 0, 0, 0);
        acc1 = __builtin_amdgcn_mfma_f32_16x16x32_bf16(al[1][kt], bh[kt], acc1, 0, 0, 0);
      }
      float mx = fmaxf(fmaxf(fmaxf(acc0[0], acc0[1]), fmaxf(acc0[2], acc0[3])),
                       fmaxf(fmaxf(acc1[0], acc1[1]), fmaxf(acc1[2], acc1[3])));
      omax[ot] = fmaxf(omax[ot], mx);
    }
  }
#pragma unroll
  for (int ot = 0; ot < 16; ++ot) {
    float v = omax[ot];
    v = fmaxf(v, __shfl_xor(v, 16, 64));
    v = fmaxf(v, __shfl_xor(v, 32, 64));
    omax[ot] = v;
  }
  if (lane < 16) {
#pragma unroll
    for (int ot = 0; ot < 16; ++ot) {
      const int o = wv * 256 + ot * 16 + lane;
      pmax[((size_t)b * 1024 + o) * 32 + nc] = omax[ot];
    }
  }
}

// ------------------- head stage 0: reduce pmax chunks + b2' -> g[8][1024]
__global__ __launch_bounds__(256) void head_g_kernel(
    const float* __restrict__ pmax, const float* __restrict__ b2p,
    float* __restrict__ gbuf) {
  const int b = blockIdx.x & 7;
  const int o = (blockIdx.x >> 3) * 256 + threadIdx.x;
  const float4* p = (const float4*)&pmax[((size_t)b * 1024 + o) * 32];
  float4 a4 = p[0];
#pragma unroll
  for (int gi = 1; gi < 8; ++gi) a4 = f4max(a4, p[gi]);
  gbuf[b * 1024 + o] = fmaxf(fmaxf(a4.x, a4.y), fmaxf(a4.z, a4.w)) + b2p[o];
}

// ------------------- head stage 1: h = relu(w2a @ g + b2a), wave-per-output
__global__ __launch_bounds__(256) void head_a_kernel(
    const float* __restrict__ gbuf, const float* __restrict__ w2a,
    const float* __restrict__ b2a, float* __restrict__ hbuf) {
  const int b = blockIdx.x & 7;
  const int k = (blockIdx.x >> 3) * 4 + (threadIdx.x >> 6);   // wave-per-output
  const int lane = threadIdx.x & 63;
  const float4* wr = (const float4*)&w2a[(size_t)k * 1024];
  const float4* gv = (const float4*)&gbuf[b * 1024];
  float a = 0.f;
#pragma unroll
  for (int i = 0; i < 4; ++i) {               // coalesced: f4 idx lane + i*64
    float4 w = wr[lane + i * 64], xx = gv[lane + i * 64];
    a += w.x * xx.x + w.y * xx.y + w.z * xx.z + w.w * xx.w;
  }
#pragma unroll
  for (int s = 32; s >= 1; s >>= 1) a += __shfl_xor(a, s, 64);
  if (lane == 0) hbuf[b * 512 + k] = fmaxf(a + b2a[k], 0.f);
}

// ------------------- head stage 2: out = w2b @ h + b2b, wave-per-output
__global__ __launch_bounds__(256) void head_b_kernel(
    const float* __restrict__ hbuf, const float* __restrict__ w2b,
    const float* __restrict__ b2b, float* __restrict__ out) {
  const int b = blockIdx.x & 7;
  const int k = (blockIdx.x >> 3) * 4 + (threadIdx.x >> 6);
  const int lane = threadIdx.x & 63;
  const float4* wr = (const float4*)&w2b[(size_t)k * 512];
  const float4* hv = (const float4*)&hbuf[b * 512];
  float a = 0.f;
#pragma unroll
  for (int i = 0; i < 2; ++i) {
    float4 w = wr[lane + i * 64], xx = hv[lane + i * 64];
    a += w.x * xx.x + w.y * xx.y + w.z * xx.z + w.w * xx.w;
  }
#pragma unroll
  for (int s = 32; s >= 1; s >>= 1) a += __shfl_xor(a, s, 64);
  if (lane == 0) out[b * 512 + k] = a + b2b[k];
}

extern "C" void kernel_launch(void* const* d_in, const int* in_sizes, int n_in,
                              void* d_out, int out_size, void* d_ws, size_t ws_size,
                              hipStream_t stream) {
  const float* pts     = (const float*)d_in[0];
  const float* w1a     = (const float*)d_in[1];
  const float* b1a     = (const float*)d_in[2];
  const float* w1b     = (const float*)d_in[3];
  const float* b1b     = (const float*)d_in[4];
  const float* w1c     = (const float*)d_in[5];
  const float* b1c     = (const float*)d_in[6];
  const float* lin1_w  = (const float*)d_in[7];
  const float* lin1_b  = (const float*)d_in[8];
  const float* conv1_w = (const float*)d_in[9];
  const float* conv1_b = (const float*)d_in[10];
  const float* lin2_w  = (const float*)d_in[11];
  const float* lin2_b  = (const float*)d_in[12];
  const float* conv2_w = (const float*)d_in[13];
  const float* conv2_b = (const float*)d_in[14];
  const float* w2a     = (const float*)d_in[15];
  const float* b2a     = (const float*)d_in[16];
  const float* w2b     = (const float*)d_in[17];
  const float* b2b     = (const float*)d_in[18];

  char* ws = (char*)d_ws;
  int*   knn_idx = (int*)ws;                              // 0 .. 1M
  float* f1  = (float*)(ws + (1u << 20));                 // 1M .. 5M
  float* pm  = (float*)(ws + (5u << 20));                 // 5M .. 6M
  unsigned short* w2hi = (unsigned short*)(ws + (6u << 20));               // 256K
  unsigned short* w2lo = (unsigned short*)(ws + (6u << 20) + (1u << 18));  // 256K
  unsigned short* w1hi = (unsigned short*)(ws + (6u << 20) + (2u << 18));  // 16K
  unsigned short* w1lo = (unsigned short*)(ws + (6u << 20) + (2u << 18) + (1u << 14));
  float* b1p = (float*)(ws + (6u << 20) + (2u << 18) + (2u << 14));        // 512B
  float* b2p = (float*)(ws + (6u << 20) + (2u << 18) + (3u << 14));        // 4K
  float* gbuf = (float*)(ws + (7u << 20));                // 32K
  float* hbuf = (float*)(ws + (7u << 20) + (1u << 16));   // 16K
  float* f2  = (float*)(ws + (9u << 20));                 // 9M .. 17M

  knn_kernel   <<<544, 512, 0, stream>>>(pts, knn_idx,
                                         lin1_w, lin1_b, conv1_w, conv1_b,
                                         lin2_w, lin2_b, conv2_w, conv2_b,
                                         w1hi, w1lo, b1p, w2hi, w2lo, b2p);
  mlp1_kernel  <<<256, 512, 0, stream>>>(pts, knn_idx, w1a, b1a, w1b, b1b, w1c, b1c, f1);
  gconv1_kernel<<<256, 256, 0, stream>>>(f1, knn_idx, w1hi, w1lo, b1p, f2);
  gconv2max_kernel<<<256, 256, 0, stream>>>(f2, knn_idx, w2hi, w2lo, pm);
  head_g_kernel<<<32, 256, 0, stream>>>(pm, b2p, gbuf);
  head_a_kernel<<<1024, 256, 0, stream>>>(gbuf, w2a, b2a, hbuf);
  head_b_kernel<<<1024, 256, 0, stream>>>(hbuf, w2b, b2b, (float*)d_out);
}